// Round 2
// baseline (4591.072 us; speedup 1.0000x reference)
//
#include <hip/hip_runtime.h>
#include <cstdint>
#include <cstddef>

// ---------------------------------------------------------------------------
// Problem constants
// ---------------------------------------------------------------------------
constexpr int N_CLASSES  = 10;
constexpr int N_INTERNAL = 256;
constexpr int N_VALS     = 2 * N_CLASSES + N_INTERNAL;  // 276
constexpr int B_SZ  = 8192;
constexpr int D_IN  = 784;
constexpr int H_DIM = 4096;

// ---------------------------------------------------------------------------
// Compile-time reconstruction of np.random.RandomState(0) circuit generation.
// Exact numpy legacy stream: MT19937 init_genrand(0); shuffle uses
// random_interval (masked rejection, 32-bit draws); randint uses masked
// rejection with rng = high-1 (32-bit draws since range < 2^32).
// ---------------------------------------------------------------------------
struct MTState {
  uint32_t key[624];
  int pos;
};

constexpr uint32_t mt_next(MTState& st) {
  if (st.pos == 624) {
    for (int i = 0; i < 624; ++i) {
      uint32_t y = (st.key[i] & 0x80000000u) | (st.key[(i + 1) % 624] & 0x7fffffffu);
      st.key[i] = st.key[(i + 397) % 624] ^ (y >> 1) ^ ((y & 1u) ? 0x9908b0dfu : 0u);
    }
    st.pos = 0;
  }
  uint32_t y = st.key[st.pos++];
  y ^= y >> 11;
  y ^= (y << 7) & 0x9d2c5680u;
  y ^= (y << 15) & 0xefc60000u;
  y ^= y >> 18;
  return y;
}

// numpy random_interval / bounded masked rejection: value in [0, maxv]
constexpr uint32_t interval_draw(MTState& st, uint32_t maxv) {
  if (maxv == 0u) return 0u;
  uint32_t mask = maxv;
  mask |= mask >> 1; mask |= mask >> 2; mask |= mask >> 4;
  mask |= mask >> 8; mask |= mask >> 16;
  uint32_t v = mt_next(st) & mask;
  while (v > maxv) v = mt_next(st) & mask;
  return v;
}

struct Circuit {
  int16_t prime[N_INTERNAL][3];
  int16_t sub[N_INTERNAL][3];
};

constexpr Circuit make_circuit() {
  MTState st{};
  uint32_t s = 0u;  // seed
  for (int i = 0; i < 624; ++i) {
    st.key[i] = s;
    s = 1812433253u * (s ^ (s >> 30)) + (uint32_t)i + 1u;
  }
  st.pos = 624;

  Circuit c{};
  for (int node = 0; node < N_INTERNAL; ++node) {
    const int avail = 2 * N_CLASSES + node;
    // choice(10, 3, replace=False) == permutation(10)[:3]
    int arr[N_CLASSES] = {0, 1, 2, 3, 4, 5, 6, 7, 8, 9};
    for (int i = N_CLASSES - 1; i >= 1; --i) {
      uint32_t j = interval_draw(st, (uint32_t)i);
      int tmp = arr[i]; arr[i] = arr[j]; arr[j] = tmp;
    }
    for (int e = 0; e < 3; ++e) c.prime[node][e] = (int16_t)arr[e];
    // randint(0, avail, 3): rng = avail-1
    for (int e = 0; e < 3; ++e) c.sub[node][e] = (int16_t)interval_draw(st, (uint32_t)(avail - 1));
  }
  return c;
}

constexpr Circuit CIRC = make_circuit();

// ---------------------------------------------------------------------------
// Circuit evaluation: fully unrolled, static indices only (register friendly)
// ---------------------------------------------------------------------------
template <int I>
__device__ __forceinline__ void eval_node(float (&vals)[N_VALS]) {
  if constexpr (I < N_INTERNAL) {
    constexpr int p0 = CIRC.prime[I][0], s0 = CIRC.sub[I][0];
    constexpr int p1 = CIRC.prime[I][1], s1 = CIRC.sub[I][1];
    constexpr int p2 = CIRC.prime[I][2], s2 = CIRC.sub[I][2];
    vals[2 * N_CLASSES + I] =
        vals[p0] * vals[s0] + vals[p1] * vals[s1] + vals[p2] * vals[s2];
    eval_node<I + 1>(vals);
  }
}

__global__ __launch_bounds__(256) void circuit_kernel(
    const float* __restrict__ probs, float* __restrict__ out, int B) {
  int r = blockIdx.x * blockDim.x + threadIdx.x;
  if (r >= B) return;
  float vals[N_VALS];
#pragma unroll
  for (int c = 0; c < N_CLASSES; ++c) {
    float p = probs[r * N_CLASSES + c];
    vals[c] = p;
    vals[N_CLASSES + c] = 1.0f - p;
  }
  eval_node<0>(vals);
  out[r] = vals[N_VALS - 1];
}

// ---------------------------------------------------------------------------
// f32 GEMM: C[M,N] = relu(A[M,K] @ W[K,N] + bias[N]); 128x128x8 tile, 256 thr
// ---------------------------------------------------------------------------
constexpr int BM = 128, BN = 128, BK = 8;

__global__ __launch_bounds__(256) void gemm_bias_relu_f32(
    const float* __restrict__ A, const float* __restrict__ W,
    const float* __restrict__ bias, float* __restrict__ C,
    int M, int N, int K) {
  __shared__ float As[BK][BM];
  __shared__ float Bs[BK][BN];

  const int t  = threadIdx.x;
  const int tx = t & 15;        // 0..15 (col group)
  const int ty = t >> 4;        // 0..15 (row group)
  const int row0 = blockIdx.y * BM;
  const int col0 = blockIdx.x * BN;

  // A staging: thread loads one float4 of A
  const int ar = t >> 1;             // 0..127
  const int ak = (t & 1) * 4;        // 0 or 4
  // B staging: thread loads one float4 of W
  const int br = t >> 5;             // 0..7
  const int bc = (t & 31) * 4;       // 0..124

  const float* Aload = A + (size_t)(row0 + ar) * K + ak;
  const float* Wload = W + (size_t)br * N + col0 + bc;

  float acc[8][8];
#pragma unroll
  for (int i = 0; i < 8; ++i)
#pragma unroll
    for (int j = 0; j < 8; ++j) acc[i][j] = 0.0f;

  for (int k0 = 0; k0 < K; k0 += BK) {
    float4 a4 = *reinterpret_cast<const float4*>(Aload + k0);
    float4 b4 = *reinterpret_cast<const float4*>(Wload + (size_t)k0 * N);
    __syncthreads();
    As[ak + 0][ar] = a4.x;
    As[ak + 1][ar] = a4.y;
    As[ak + 2][ar] = a4.z;
    As[ak + 3][ar] = a4.w;
    *reinterpret_cast<float4*>(&Bs[br][bc]) = b4;
    __syncthreads();
#pragma unroll
    for (int kk = 0; kk < BK; ++kk) {
      float a[8], b[8];
      *reinterpret_cast<float4*>(&a[0]) = *reinterpret_cast<const float4*>(&As[kk][ty * 4]);
      *reinterpret_cast<float4*>(&a[4]) = *reinterpret_cast<const float4*>(&As[kk][64 + ty * 4]);
      *reinterpret_cast<float4*>(&b[0]) = *reinterpret_cast<const float4*>(&Bs[kk][tx * 4]);
      *reinterpret_cast<float4*>(&b[4]) = *reinterpret_cast<const float4*>(&Bs[kk][64 + tx * 4]);
#pragma unroll
      for (int i = 0; i < 8; ++i)
#pragma unroll
        for (int j = 0; j < 8; ++j) acc[i][j] = fmaf(a[i], b[j], acc[i][j]);
    }
  }

  // epilogue: bias + relu, float4 stores (contiguous across tx)
#pragma unroll
  for (int ih = 0; ih < 2; ++ih) {
#pragma unroll
    for (int i = 0; i < 4; ++i) {
      const int row = row0 + ih * 64 + ty * 4 + i;
#pragma unroll
      for (int jh = 0; jh < 2; ++jh) {
        const int col = col0 + jh * 64 + tx * 4;
        float4 bv = *reinterpret_cast<const float4*>(bias + col);
        float4 o;
        o.x = fmaxf(acc[ih * 4 + i][jh * 4 + 0] + bv.x, 0.0f);
        o.y = fmaxf(acc[ih * 4 + i][jh * 4 + 1] + bv.y, 0.0f);
        o.z = fmaxf(acc[ih * 4 + i][jh * 4 + 2] + bv.z, 0.0f);
        o.w = fmaxf(acc[ih * 4 + i][jh * 4 + 3] + bv.w, 0.0f);
        *reinterpret_cast<float4*>(C + (size_t)row * N + col) = o;
      }
    }
  }
}

// ---------------------------------------------------------------------------
// logits (K=4096, N=10) + softmax -> probs[B,10]; one wave per row
// ---------------------------------------------------------------------------
__global__ __launch_bounds__(256) void logits_softmax_kernel(
    const float* __restrict__ h2, const float* __restrict__ W3,
    const float* __restrict__ b3, float* __restrict__ probs, int B) {
  const int wave = threadIdx.x >> 6;
  const int lane = threadIdx.x & 63;
  const int row  = blockIdx.x * 4 + wave;
  if (row >= B) return;

  const float* hrow = h2 + (size_t)row * H_DIM;
  float acc[N_CLASSES];
#pragma unroll
  for (int c = 0; c < N_CLASSES; ++c) acc[c] = 0.0f;

#pragma unroll 4
  for (int it = 0; it < H_DIM / (64 * 4); ++it) {
    const int k0 = (it * 64 + lane) * 4;
    float4 h4 = *reinterpret_cast<const float4*>(hrow + k0);
    const float hv[4] = {h4.x, h4.y, h4.z, h4.w};
#pragma unroll
    for (int q = 0; q < 4; ++q) {
      const float* wrow = W3 + (size_t)(k0 + q) * N_CLASSES;
#pragma unroll
      for (int c = 0; c < N_CLASSES; ++c) acc[c] = fmaf(hv[q], wrow[c], acc[c]);
    }
  }

#pragma unroll
  for (int c = 0; c < N_CLASSES; ++c) {
#pragma unroll
    for (int s = 32; s >= 1; s >>= 1) acc[c] += __shfl_xor(acc[c], s, 64);
  }

  if (lane == 0) {
    float l[N_CLASSES], m = -3.0e38f;
#pragma unroll
    for (int c = 0; c < N_CLASSES; ++c) {
      l[c] = acc[c] + b3[c];
      m = fmaxf(m, l[c]);
    }
    float sum = 0.0f;
#pragma unroll
    for (int c = 0; c < N_CLASSES; ++c) {
      l[c] = expf(l[c] - m);
      sum += l[c];
    }
    const float inv = 1.0f / sum;
#pragma unroll
    for (int c = 0; c < N_CLASSES; ++c) probs[row * N_CLASSES + c] = l[c] * inv;
  }
}

// ---------------------------------------------------------------------------
// launch — ws_size-adaptive row chunking (R rows per chunk, multiple of 256).
// Per chunk: h1[R,4096] f32 + h2[R,4096] f32 + probs[R,10] f32.
// ---------------------------------------------------------------------------
extern "C" void kernel_launch(void* const* d_in, const int* in_sizes, int n_in,
                              void* d_out, int out_size, void* d_ws, size_t ws_size,
                              hipStream_t stream) {
  const float* x  = (const float*)d_in[0];
  const float* W1 = (const float*)d_in[1];
  const float* b1 = (const float*)d_in[2];
  const float* W2 = (const float*)d_in[3];
  const float* b2 = (const float*)d_in[4];
  const float* W3 = (const float*)d_in[5];
  const float* b3 = (const float*)d_in[6];
  float* out = (float*)d_out;

  // Choose chunk rows R (multiple of 256) fitting in ws_size.
  const size_t per_row = (size_t)2 * H_DIM * sizeof(float) + N_CLASSES * sizeof(float);
  size_t rcap = ws_size / per_row;
  int R = (int)((rcap / 256) * 256);
  if (R > B_SZ) R = B_SZ;
  if (R < 256) R = 256;  // minimum viable chunk (4 MiB + 8 MiB); below this nothing fits

  float* h1    = (float*)d_ws;
  float* h2    = h1 + (size_t)R * H_DIM;
  float* probs = h2 + (size_t)R * H_DIM;

  dim3 blk(256);

  for (int r0 = 0; r0 < B_SZ; r0 += R) {
    const int rows = (B_SZ - r0 < R) ? (B_SZ - r0) : R;  // multiple of 256

    // layer 1: h1 = relu(x_chunk @ W1 + b1)   [rows,784]x[784,4096]
    gemm_bias_relu_f32<<<dim3(H_DIM / BN, rows / BM), blk, 0, stream>>>(
        x + (size_t)r0 * D_IN, W1, b1, h1, rows, H_DIM, D_IN);

    // layer 2: h2 = relu(h1 @ W2 + b2)  [rows,4096]x[4096,4096]
    gemm_bias_relu_f32<<<dim3(H_DIM / BN, rows / BM), blk, 0, stream>>>(
        h1, W2, b2, h2, rows, H_DIM, H_DIM);

    // layer 3 + softmax -> probs
    logits_softmax_kernel<<<dim3(rows / 4), blk, 0, stream>>>(h2, W3, b3, probs, rows);

    // circuit eval -> out[rows]
    circuit_kernel<<<dim3(rows / 256), blk, 0, stream>>>(probs, out + r0, rows);
  }
}

// Round 3
// 582.815 us; speedup vs baseline: 7.8774x; 7.8774x over previous
//
#include <hip/hip_runtime.h>
#include <cstdint>
#include <cstddef>

// ---------------------------------------------------------------------------
// Problem constants
// ---------------------------------------------------------------------------
constexpr int N_CLASSES  = 10;
constexpr int N_INTERNAL = 256;
constexpr int N_VALS     = 2 * N_CLASSES + N_INTERNAL;  // 276
constexpr int B_SZ  = 8192;
constexpr int D_IN  = 784;
constexpr int KP1   = 800;    // D_IN padded to multiple of 32
constexpr int H_DIM = 4096;

// ---------------------------------------------------------------------------
// Compile-time reconstruction of np.random.RandomState(0) circuit generation.
// (verified bit-exact in round 2: absmax == 0.0)
// ---------------------------------------------------------------------------
struct MTState {
  uint32_t key[624];
  int pos;
};

constexpr uint32_t mt_next(MTState& st) {
  if (st.pos == 624) {
    for (int i = 0; i < 624; ++i) {
      uint32_t y = (st.key[i] & 0x80000000u) | (st.key[(i + 1) % 624] & 0x7fffffffu);
      st.key[i] = st.key[(i + 397) % 624] ^ (y >> 1) ^ ((y & 1u) ? 0x9908b0dfu : 0u);
    }
    st.pos = 0;
  }
  uint32_t y = st.key[st.pos++];
  y ^= y >> 11;
  y ^= (y << 7) & 0x9d2c5680u;
  y ^= (y << 15) & 0xefc60000u;
  y ^= y >> 18;
  return y;
}

constexpr uint32_t interval_draw(MTState& st, uint32_t maxv) {
  if (maxv == 0u) return 0u;
  uint32_t mask = maxv;
  mask |= mask >> 1; mask |= mask >> 2; mask |= mask >> 4;
  mask |= mask >> 8; mask |= mask >> 16;
  uint32_t v = mt_next(st) & mask;
  while (v > maxv) v = mt_next(st) & mask;
  return v;
}

struct Circuit {
  int16_t prime[N_INTERNAL][3];
  int16_t sub[N_INTERNAL][3];
};

constexpr Circuit make_circuit() {
  MTState st{};
  uint32_t s = 0u;
  for (int i = 0; i < 624; ++i) {
    st.key[i] = s;
    s = 1812433253u * (s ^ (s >> 30)) + (uint32_t)i + 1u;
  }
  st.pos = 624;

  Circuit c{};
  for (int node = 0; node < N_INTERNAL; ++node) {
    const int avail = 2 * N_CLASSES + node;
    int arr[N_CLASSES] = {0, 1, 2, 3, 4, 5, 6, 7, 8, 9};
    for (int i = N_CLASSES - 1; i >= 1; --i) {
      uint32_t j = interval_draw(st, (uint32_t)i);
      int tmp = arr[i]; arr[i] = arr[j]; arr[j] = tmp;
    }
    for (int e = 0; e < 3; ++e) c.prime[node][e] = (int16_t)arr[e];
    for (int e = 0; e < 3; ++e) c.sub[node][e] = (int16_t)interval_draw(st, (uint32_t)(avail - 1));
  }
  return c;
}

constexpr Circuit CIRC = make_circuit();

// ---------------------------------------------------------------------------
// helpers
// ---------------------------------------------------------------------------
__device__ __forceinline__ uint16_t f2bf(float f) {
  uint32_t u = __builtin_bit_cast(uint32_t, f);
  uint32_t r = (u + 0x7fffu + ((u >> 16) & 1u)) >> 16;  // RNE
  return (uint16_t)r;
}
__device__ __forceinline__ float bf2f(uint16_t h) {
  uint32_t u = ((uint32_t)h) << 16;
  return __builtin_bit_cast(float, u);
}

__device__ __forceinline__ void load_lds16(const void* g, void* l) {
  __builtin_amdgcn_global_load_lds(
      (const __attribute__((address_space(1))) unsigned int*)g,
      (__attribute__((address_space(3))) unsigned int*)l, 16, 0, 0);
}

using bf16x8 = __attribute__((ext_vector_type(8))) short;
using f32x4  = __attribute__((ext_vector_type(4))) float;

// ---------------------------------------------------------------------------
// Circuit evaluation: fully unrolled, static indices only
// ---------------------------------------------------------------------------
template <int I>
__device__ __forceinline__ void eval_node(float (&vals)[N_VALS]) {
  if constexpr (I < N_INTERNAL) {
    constexpr int p0 = CIRC.prime[I][0], s0 = CIRC.sub[I][0];
    constexpr int p1 = CIRC.prime[I][1], s1 = CIRC.sub[I][1];
    constexpr int p2 = CIRC.prime[I][2], s2 = CIRC.sub[I][2];
    vals[2 * N_CLASSES + I] =
        vals[p0] * vals[s0] + vals[p1] * vals[s1] + vals[p2] * vals[s2];
    eval_node<I + 1>(vals);
  }
}

__global__ __launch_bounds__(256) void circuit_kernel(
    const float* __restrict__ probs, float* __restrict__ out, int B) {
  int r = blockIdx.x * blockDim.x + threadIdx.x;
  if (r >= B) return;
  float vals[N_VALS];
#pragma unroll
  for (int c = 0; c < N_CLASSES; ++c) {
    float p = probs[r * N_CLASSES + c];
    vals[c] = p;
    vals[N_CLASSES + c] = 1.0f - p;
  }
  eval_node<0>(vals);
  out[r] = vals[N_VALS - 1];
}

// ---------------------------------------------------------------------------
// x [B,784] f32 -> xb [B,800] bf16 (zero-padded)
// ---------------------------------------------------------------------------
__global__ __launch_bounds__(256) void convert_pad_x(
    const float* __restrict__ x, uint16_t* __restrict__ xb) {
  int idx = blockIdx.x * 256 + threadIdx.x;
  if (idx >= B_SZ * KP1) return;
  int r = idx / KP1, c = idx - r * KP1;
  xb[idx] = (c < D_IN) ? f2bf(x[(size_t)r * D_IN + c]) : (uint16_t)0;
}

// ---------------------------------------------------------------------------
// W [K,N] f32 -> Wt [N,Kp] bf16 (transpose + convert, zero-pad k in [K,Kp))
// ---------------------------------------------------------------------------
__global__ __launch_bounds__(256) void transpose_convert(
    const float* __restrict__ W, uint16_t* __restrict__ Wt,
    int K, int N, int Kp) {
  __shared__ float tile[32][33];
  const int kt = blockIdx.y * 32;
  const int nt = blockIdx.x * 32;
  const int tc = threadIdx.x & 31;
  const int tr = threadIdx.x >> 5;  // 0..7
#pragma unroll
  for (int i = 0; i < 4; ++i) {
    int k = kt + tr + i * 8;
    tile[tr + i * 8][tc] = (k < K) ? W[(size_t)k * N + nt + tc] : 0.0f;
  }
  __syncthreads();
#pragma unroll
  for (int i = 0; i < 4; ++i) {
    int n = nt + tr + i * 8;
    int k = kt + tc;
    if (k < Kp) Wt[(size_t)n * Kp + k] = f2bf(tile[tc][tr + i * 8]);
  }
}

// ---------------------------------------------------------------------------
// bf16 MFMA GEMM (m97 structure): C[M,N] = relu(A[M,K] @ Bt[N,K]^T + bias)
// 128x128 tile, BK=32, 256 threads (4 waves, 2x2 of 64x64), global_load_lds.
// A, Bt bf16 row-major; C bf16 row-major. M,N mult of 128; K mult of 32.
// ---------------------------------------------------------------------------
__global__ __launch_bounds__(256) void gemm_bt_bf16(
    const uint16_t* __restrict__ A, const uint16_t* __restrict__ Bt,
    const float* __restrict__ bias, uint16_t* __restrict__ C,
    int M, int N, int K) {
  __shared__ uint16_t As[128 * 32];
  __shared__ uint16_t Bs[128 * 32];

  const int t    = threadIdx.x;
  const int lane = t & 63;
  const int wv   = t >> 6;
  const int wr   = wv >> 1;        // wave row 0..1
  const int wc   = wv & 1;         // wave col 0..1
  const int fr   = lane & 15;      // fragment row/col within 16
  const int fq   = lane >> 4;      // k-quad 0..3
  const int row0 = blockIdx.y * 128;
  const int col0 = blockIdx.x * 128;

  // staging: linear byte offsets o and o+4096 in an 8KB tile; row = o/64
  const int o1 = t * 16;
  const int o2 = o1 + 4096;
  const int ar1 = o1 >> 6, ab1 = o1 & 63;
  const int ar2 = o2 >> 6, ab2 = o2 & 63;

  const char* Abytes = (const char*)A;
  const char* Bbytes = (const char*)Bt;

  f32x4 acc[4][4];
#pragma unroll
  for (int m = 0; m < 4; ++m)
#pragma unroll
    for (int n = 0; n < 4; ++n) {
      acc[m][n][0] = 0.f; acc[m][n][1] = 0.f; acc[m][n][2] = 0.f; acc[m][n][3] = 0.f;
    }

  for (int k0 = 0; k0 < K; k0 += 32) {
    __syncthreads();  // previous iteration's LDS reads complete
    const size_t kb = (size_t)k0 * 2;
    load_lds16(Abytes + ((size_t)(row0 + ar1) * K) * 2 + kb + ab1, (char*)As + o1);
    load_lds16(Abytes + ((size_t)(row0 + ar2) * K) * 2 + kb + ab2, (char*)As + o2);
    load_lds16(Bbytes + ((size_t)(col0 + ar1) * K) * 2 + kb + ab1, (char*)Bs + o1);
    load_lds16(Bbytes + ((size_t)(col0 + ar2) * K) * 2 + kb + ab2, (char*)Bs + o2);
    __syncthreads();  // vmcnt(0) drained by compiler before barrier

    bf16x8 a[4], b[4];
#pragma unroll
    for (int m = 0; m < 4; ++m)
      a[m] = *(const bf16x8*)&As[(wr * 64 + m * 16 + fr) * 32 + fq * 8];
#pragma unroll
    for (int n = 0; n < 4; ++n)
      b[n] = *(const bf16x8*)&Bs[(wc * 64 + n * 16 + fr) * 32 + fq * 8];
#pragma unroll
    for (int m = 0; m < 4; ++m)
#pragma unroll
      for (int n = 0; n < 4; ++n)
        acc[m][n] = __builtin_amdgcn_mfma_f32_16x16x32_bf16(a[m], b[n], acc[m][n], 0, 0, 0);
  }

  // epilogue: bias + relu + bf16 store
  // C/D layout: col = lane&15, row = (lane>>4)*4 + j   [measured m89]
#pragma unroll
  for (int n = 0; n < 4; ++n) {
    const int col = col0 + wc * 64 + n * 16 + fr;
    const float bv = bias[col];
#pragma unroll
    for (int m = 0; m < 4; ++m) {
      const int row = row0 + wr * 64 + m * 16 + fq * 4;
      size_t base = (size_t)row * N + col;
#pragma unroll
      for (int j = 0; j < 4; ++j) {
        float v = acc[m][n][j] + bv;
        v = fmaxf(v, 0.0f);
        C[base + (size_t)j * N] = f2bf(v);
      }
    }
  }
}

// ---------------------------------------------------------------------------
// logits (K=4096, N=10) + softmax -> probs[B,10]; one wave per row; h2 bf16
// ---------------------------------------------------------------------------
__global__ __launch_bounds__(256) void logits_softmax_kernel(
    const uint16_t* __restrict__ h2, const float* __restrict__ W3,
    const float* __restrict__ b3, float* __restrict__ probs, int B) {
  const int wave = threadIdx.x >> 6;
  const int lane = threadIdx.x & 63;
  const int row  = blockIdx.x * 4 + wave;
  if (row >= B) return;

  const uint16_t* hrow = h2 + (size_t)row * H_DIM;
  float acc[N_CLASSES];
#pragma unroll
  for (int c = 0; c < N_CLASSES; ++c) acc[c] = 0.0f;

#pragma unroll
  for (int it = 0; it < H_DIM / (64 * 8); ++it) {
    const int k0 = (it * 64 + lane) * 8;
    ushort4 u0 = *reinterpret_cast<const ushort4*>(hrow + k0);
    ushort4 u1 = *reinterpret_cast<const ushort4*>(hrow + k0 + 4);
    float hv[8] = {bf2f(u0.x), bf2f(u0.y), bf2f(u0.z), bf2f(u0.w),
                   bf2f(u1.x), bf2f(u1.y), bf2f(u1.z), bf2f(u1.w)};
#pragma unroll
    for (int q = 0; q < 8; ++q) {
      const float* wrow = W3 + (size_t)(k0 + q) * N_CLASSES;
#pragma unroll
      for (int c = 0; c < N_CLASSES; ++c) acc[c] = fmaf(hv[q], wrow[c], acc[c]);
    }
  }

#pragma unroll
  for (int c = 0; c < N_CLASSES; ++c) {
#pragma unroll
    for (int s = 32; s >= 1; s >>= 1) acc[c] += __shfl_xor(acc[c], s, 64);
  }

  if (lane == 0) {
    float l[N_CLASSES], m = -3.0e38f;
#pragma unroll
    for (int c = 0; c < N_CLASSES; ++c) {
      l[c] = acc[c] + b3[c];
      m = fmaxf(m, l[c]);
    }
    float sum = 0.0f;
#pragma unroll
    for (int c = 0; c < N_CLASSES; ++c) {
      l[c] = expf(l[c] - m);
      sum += l[c];
    }
    const float inv = 1.0f / sum;
#pragma unroll
    for (int c = 0; c < N_CLASSES; ++c) probs[row * N_CLASSES + c] = l[c] * inv;
  }
}

// ---------------------------------------------------------------------------
// launch.  ws layout (bf16 unless noted), total ~188 MB (ws >= 256 MB, R2):
//   xb[8192*800] w1t[4096*800] w2t[4096*4096] h1[8192*4096] h2[8192*4096]
//   probs f32[8192*10]
// ---------------------------------------------------------------------------
extern "C" void kernel_launch(void* const* d_in, const int* in_sizes, int n_in,
                              void* d_out, int out_size, void* d_ws, size_t ws_size,
                              hipStream_t stream) {
  const float* x  = (const float*)d_in[0];
  const float* W1 = (const float*)d_in[1];
  const float* b1 = (const float*)d_in[2];
  const float* W2 = (const float*)d_in[3];
  const float* b2 = (const float*)d_in[4];
  const float* W3 = (const float*)d_in[5];
  const float* b3 = (const float*)d_in[6];
  float* out = (float*)d_out;

  uint16_t* xb  = (uint16_t*)d_ws;
  uint16_t* w1t = xb  + (size_t)B_SZ * KP1;
  uint16_t* w2t = w1t + (size_t)H_DIM * KP1;
  uint16_t* h1  = w2t + (size_t)H_DIM * H_DIM;
  uint16_t* h2  = h1  + (size_t)B_SZ * H_DIM;
  float* probs  = (float*)(h2 + (size_t)B_SZ * H_DIM);

  dim3 blk(256);

  // input conversions
  convert_pad_x<<<dim3((B_SZ * KP1 + 255) / 256), blk, 0, stream>>>(x, xb);
  transpose_convert<<<dim3(H_DIM / 32, KP1 / 32), blk, 0, stream>>>(W1, w1t, D_IN, H_DIM, KP1);
  transpose_convert<<<dim3(H_DIM / 32, H_DIM / 32), blk, 0, stream>>>(W2, w2t, H_DIM, H_DIM, H_DIM);

  // layer 1: h1 = relu(xb @ w1t^T + b1)   [8192,800]x[800,4096]
  gemm_bt_bf16<<<dim3(H_DIM / 128, B_SZ / 128), blk, 0, stream>>>(
      xb, w1t, b1, h1, B_SZ, H_DIM, KP1);

  // layer 2: h2 = relu(h1 @ w2t^T + b2)   [8192,4096]x[4096,4096]
  gemm_bt_bf16<<<dim3(H_DIM / 128, B_SZ / 128), blk, 0, stream>>>(
      h1, w2t, b2, h2, B_SZ, H_DIM, H_DIM);

  // layer 3 + softmax -> probs
  logits_softmax_kernel<<<dim3(B_SZ / 4), blk, 0, stream>>>(h2, W3, b3, probs, B_SZ);

  // circuit eval -> out[B]
  circuit_kernel<<<dim3(B_SZ / 256), blk, 0, stream>>>(probs, out, B_SZ);
}

// Round 4
// 527.783 us; speedup vs baseline: 8.6988x; 1.1043x over previous
//
#include <hip/hip_runtime.h>
#include <cstdint>
#include <cstddef>

// ---------------------------------------------------------------------------
// Problem constants
// ---------------------------------------------------------------------------
constexpr int N_CLASSES  = 10;
constexpr int N_INTERNAL = 256;
constexpr int N_VALS     = 2 * N_CLASSES + N_INTERNAL;  // 276
constexpr int B_SZ  = 8192;
constexpr int D_IN  = 784;
constexpr int KP1   = 896;    // D_IN padded to multiple of 128 (8-phase needs K%128==0)
constexpr int H_DIM = 4096;

// ---------------------------------------------------------------------------
// Compile-time reconstruction of np.random.RandomState(0) circuit generation.
// (verified bit-exact in round 2: absmax == 0.0)
// ---------------------------------------------------------------------------
struct MTState {
  uint32_t key[624];
  int pos;
};

constexpr uint32_t mt_next(MTState& st) {
  if (st.pos == 624) {
    for (int i = 0; i < 624; ++i) {
      uint32_t y = (st.key[i] & 0x80000000u) | (st.key[(i + 1) % 624] & 0x7fffffffu);
      st.key[i] = st.key[(i + 397) % 624] ^ (y >> 1) ^ ((y & 1u) ? 0x9908b0dfu : 0u);
    }
    st.pos = 0;
  }
  uint32_t y = st.key[st.pos++];
  y ^= y >> 11;
  y ^= (y << 7) & 0x9d2c5680u;
  y ^= (y << 15) & 0xefc60000u;
  y ^= y >> 18;
  return y;
}

constexpr uint32_t interval_draw(MTState& st, uint32_t maxv) {
  if (maxv == 0u) return 0u;
  uint32_t mask = maxv;
  mask |= mask >> 1; mask |= mask >> 2; mask |= mask >> 4;
  mask |= mask >> 8; mask |= mask >> 16;
  uint32_t v = mt_next(st) & mask;
  while (v > maxv) v = mt_next(st) & mask;
  return v;
}

struct Circuit {
  int16_t prime[N_INTERNAL][3];
  int16_t sub[N_INTERNAL][3];
};

constexpr Circuit make_circuit() {
  MTState st{};
  uint32_t s = 0u;
  for (int i = 0; i < 624; ++i) {
    st.key[i] = s;
    s = 1812433253u * (s ^ (s >> 30)) + (uint32_t)i + 1u;
  }
  st.pos = 624;

  Circuit c{};
  for (int node = 0; node < N_INTERNAL; ++node) {
    const int avail = 2 * N_CLASSES + node;
    int arr[N_CLASSES] = {0, 1, 2, 3, 4, 5, 6, 7, 8, 9};
    for (int i = N_CLASSES - 1; i >= 1; --i) {
      uint32_t j = interval_draw(st, (uint32_t)i);
      int tmp = arr[i]; arr[i] = arr[j]; arr[j] = tmp;
    }
    for (int e = 0; e < 3; ++e) c.prime[node][e] = (int16_t)arr[e];
    for (int e = 0; e < 3; ++e) c.sub[node][e] = (int16_t)interval_draw(st, (uint32_t)(avail - 1));
  }
  return c;
}

constexpr Circuit CIRC = make_circuit();

// ---------------------------------------------------------------------------
// helpers
// ---------------------------------------------------------------------------
__device__ __forceinline__ uint16_t f2bf(float f) {
  uint32_t u = __builtin_bit_cast(uint32_t, f);
  uint32_t r = (u + 0x7fffu + ((u >> 16) & 1u)) >> 16;  // RNE
  return (uint16_t)r;
}
__device__ __forceinline__ float bf2f(uint16_t h) {
  uint32_t u = ((uint32_t)h) << 16;
  return __builtin_bit_cast(float, u);
}

__device__ __forceinline__ void load_lds16(const void* g, void* l) {
  __builtin_amdgcn_global_load_lds(
      (const __attribute__((address_space(1))) unsigned int*)g,
      (__attribute__((address_space(3))) unsigned int*)l, 16, 0, 0);
}

using bf16x8 = __attribute__((ext_vector_type(8))) short;
using f32x4  = __attribute__((ext_vector_type(4))) float;

__device__ __forceinline__ void dsr(bf16x8& d, uint32_t a) {
  asm volatile("ds_read_b128 %0, %1" : "=v"(d) : "v"(a));
}

// ---------------------------------------------------------------------------
// Circuit evaluation: fully unrolled, static indices only
// ---------------------------------------------------------------------------
template <int I>
__device__ __forceinline__ void eval_node(float (&vals)[N_VALS]) {
  if constexpr (I < N_INTERNAL) {
    constexpr int p0 = CIRC.prime[I][0], s0 = CIRC.sub[I][0];
    constexpr int p1 = CIRC.prime[I][1], s1 = CIRC.sub[I][1];
    constexpr int p2 = CIRC.prime[I][2], s2 = CIRC.sub[I][2];
    vals[2 * N_CLASSES + I] =
        vals[p0] * vals[s0] + vals[p1] * vals[s1] + vals[p2] * vals[s2];
    eval_node<I + 1>(vals);
  }
}

__global__ __launch_bounds__(256) void circuit_kernel(
    const float* __restrict__ probs, float* __restrict__ out, int B) {
  int r = blockIdx.x * blockDim.x + threadIdx.x;
  if (r >= B) return;
  float vals[N_VALS];
#pragma unroll
  for (int c = 0; c < N_CLASSES; ++c) {
    float p = probs[r * N_CLASSES + c];
    vals[c] = p;
    vals[N_CLASSES + c] = 1.0f - p;
  }
  eval_node<0>(vals);
  out[r] = vals[N_VALS - 1];
}

// ---------------------------------------------------------------------------
// x [B,784] f32 -> xb [B,896] bf16 (zero-padded)
// ---------------------------------------------------------------------------
__global__ __launch_bounds__(256) void convert_pad_x(
    const float* __restrict__ x, uint16_t* __restrict__ xb) {
  int idx = blockIdx.x * 256 + threadIdx.x;
  if (idx >= B_SZ * KP1) return;
  int r = idx / KP1, c = idx - r * KP1;
  xb[idx] = (c < D_IN) ? f2bf(x[(size_t)r * D_IN + c]) : (uint16_t)0;
}

// ---------------------------------------------------------------------------
// W [K,N] f32 -> Wt [N,Kp] bf16 (transpose + convert, zero-pad k in [K,Kp))
// ---------------------------------------------------------------------------
__global__ __launch_bounds__(256) void transpose_convert(
    const float* __restrict__ W, uint16_t* __restrict__ Wt,
    int K, int N, int Kp) {
  __shared__ float tile[32][33];
  const int kt = blockIdx.y * 32;
  const int nt = blockIdx.x * 32;
  const int tc = threadIdx.x & 31;
  const int tr = threadIdx.x >> 5;  // 0..7
#pragma unroll
  for (int i = 0; i < 4; ++i) {
    int k = kt + tr + i * 8;
    tile[tr + i * 8][tc] = (k < K) ? W[(size_t)k * N + nt + tc] : 0.0f;
  }
  __syncthreads();
#pragma unroll
  for (int i = 0; i < 4; ++i) {
    int n = nt + tr + i * 8;
    int k = kt + tc;
    if (k < Kp) Wt[(size_t)n * Kp + k] = f2bf(tile[tc][tr + i * 8]);
  }
}

// ---------------------------------------------------------------------------
// 256x256 8-phase bf16 MFMA GEMM (m201-style template, derived from scratch):
//   C[M,N] = relu(A[M,K] @ Bt[N,K]^T + bias[N]), bf16 in/out, f32 accum.
// 512 threads = 8 waves (2Mx4N), per-wave 128x64 output. BK=64, 2 K-tiles/iter,
// 8 phases/iter. LDS 128 KiB: A[2][256][64] + B[2][256][64] bf16, with row
// permutation (contiguous dead half-tiles) + slot^=(row&7) XOR swizzle.
// Staging: global_load_lds width 16, linear LDS dest + inverse-swizzled source.
// Counted vmcnt(6) at phases 4/8 only; raw s_barrier; setprio around MFMA.
// Requires: M%256==0, N%256==0, K%128==0, K>=256.
// ---------------------------------------------------------------------------
template <int MH, int NH, bool RB, int VM, typename F>
__device__ __forceinline__ void phase_t(
    uint32_t aB, uint32_t bB, uint32_t s0v, uint32_t s1v,
    bf16x8 (&Ar)[4][2], bf16x8 (&Br)[2][2], f32x4 (&acc)[2][2][4][2],
    F&& stage) {
  // 1. ds_read fragments (volatile asm — pinned within the phase's barriers)
#pragma unroll
  for (int m = 0; m < 4; ++m) {
    dsr(Ar[m][0], aB + MH * 16384 + m * 2048 + s0v);
    dsr(Ar[m][1], aB + MH * 16384 + m * 2048 + s1v);
  }
  if constexpr (RB) {
#pragma unroll
    for (int nf = 0; nf < 2; ++nf) {
      dsr(Br[nf][0], bB + NH * 16384 + nf * 2048 + s0v);
      dsr(Br[nf][1], bB + NH * 16384 + nf * 2048 + s1v);
    }
  }
  // 2. stage issues (global_load_lds) for this phase
  stage();
  // 3. barrier; wait LDS reads; MFMA cluster
  __builtin_amdgcn_s_barrier();
  asm volatile("s_waitcnt lgkmcnt(0)" ::: "memory");
  __builtin_amdgcn_sched_barrier(0);  // rule #18: pin MFMAs below the wait
  __builtin_amdgcn_s_setprio(1);
#pragma unroll
  for (int m = 0; m < 4; ++m)
#pragma unroll
    for (int nf = 0; nf < 2; ++nf) {
      acc[MH][NH][m][nf] = __builtin_amdgcn_mfma_f32_16x16x32_bf16(
          Ar[m][0], Br[nf][0], acc[MH][NH][m][nf], 0, 0, 0);
      acc[MH][NH][m][nf] = __builtin_amdgcn_mfma_f32_16x16x32_bf16(
          Ar[m][1], Br[nf][1], acc[MH][NH][m][nf], 0, 0, 0);
    }
  __builtin_amdgcn_s_setprio(0);
  // 4. counted vmcnt (confirms the tile read after the NEXT barrier)
  if constexpr (VM >= 0) asm volatile("s_waitcnt vmcnt(%0)" :: "i"(VM) : "memory");
  __builtin_amdgcn_s_barrier();
}

__global__ __launch_bounds__(512, 2) void gemm256_bf16(
    const uint16_t* __restrict__ A, const uint16_t* __restrict__ Bt,
    const float* __restrict__ bias, uint16_t* __restrict__ C,
    int M, int N, int K) {
  extern __shared__ char smem[];

  const int t    = threadIdx.x;
  const int t16  = t * 16;
  const int lane = t & 63;
  const int wid  = t >> 6;
  const int wr   = wid >> 2;   // 0..1
  const int wc   = wid & 3;    // 0..3
  const int fr   = lane & 15;
  const int fq   = lane >> 4;

  // XCD-aware bijective swizzle (nwg % 8 == 0 for both layers)
  const int gx = gridDim.x, gy = gridDim.y;
  const int nwg = gx * gy;
  const int id  = blockIdx.y * gx + blockIdx.x;
  const int cpx = nwg >> 3;
  const int sid = (id & 7) * cpx + (id >> 3);
  const int row0 = (sid / gx) * 256;
  const int col0 = (sid % gx) * 256;

  const size_t Kb = (size_t)K * 2;
  const char* Ab = (const char*)A;
  const char* Bb = (const char*)Bt;

  // ---- per-thread staging source offsets (inverse swizzle + row permutation)
  size_t srcA00, srcA01, srcA10, srcA11, srcB00, srcB01, srcB10, srcB11;
#define MKSRC(h, j, SA_, SB_) { \
    const int off_ = (j) * 8192 + t16; \
    const int p_ = (h) * 128 + (off_ >> 7); \
    const int s_ = (off_ >> 4) & 7, sg_ = s_ ^ (p_ & 7); \
    const int ga_ = (((p_ >> 6) & 1) * 128) + (h) * 64 + (p_ & 63); \
    const int gb_ = (((p_ >> 5) & 3) * 64) + (h) * 32 + (p_ & 31); \
    SA_ = (size_t)(row0 + ga_) * Kb + sg_ * 16; \
    SB_ = (size_t)(col0 + gb_) * Kb + sg_ * 16; }
  MKSRC(0, 0, srcA00, srcB00)
  MKSRC(0, 1, srcA01, srcB01)
  MKSRC(1, 0, srcA10, srcB10)
  MKSRC(1, 1, srcA11, srcB11)
#undef MKSRC

#define STAGE_A(v, h, kt) do { const char* g_ = Ab + (size_t)(kt) * 128; \
    load_lds16(g_ + srcA##h##0, smem + (v) * 32768 + (h) * 16384 + t16); \
    load_lds16(g_ + srcA##h##1, smem + (v) * 32768 + (h) * 16384 + 8192 + t16); } while (0)
#define STAGE_B(v, h, kt) do { const char* g_ = Bb + (size_t)(kt) * 128; \
    load_lds16(g_ + srcB##h##0, smem + 65536 + (v) * 32768 + (h) * 16384 + t16); \
    load_lds16(g_ + srcB##h##1, smem + 65536 + (v) * 32768 + (h) * 16384 + 8192 + t16); } while (0)

  // ---- per-thread ds_read bases (swizzled)
  const uint32_t smb = (uint32_t)(size_t)(__attribute__((address_space(3))) char*)smem;
  const uint32_t aB0 = smb + (uint32_t)((wr * 64 + fr) * 128);
  const uint32_t bB0 = smb + 65536u + (uint32_t)((wc * 32 + fr) * 128);
  const uint32_t s0v = (uint32_t)(((0 * 4 + fq) ^ (fr & 7)) * 16);
  const uint32_t s1v = (uint32_t)(((1 * 4 + fq) ^ (fr & 7)) * 16);

  f32x4 acc[2][2][4][2];
#pragma unroll
  for (int a = 0; a < 2; ++a)
#pragma unroll
    for (int b = 0; b < 2; ++b)
#pragma unroll
      for (int m = 0; m < 4; ++m)
#pragma unroll
        for (int n = 0; n < 2; ++n) {
          acc[a][b][m][n][0] = 0.f; acc[a][b][m][n][1] = 0.f;
          acc[a][b][m][n][2] = 0.f; acc[a][b][m][n][3] = 0.f;
        }

  bf16x8 Ar[4][2], Br[2][2];

  // ---- prologue: tile0 fully, tile1 minus A1; confirm tile0; barrier
  STAGE_B(0, 0, 0); STAGE_A(0, 0, 0); STAGE_B(0, 1, 0); STAGE_A(0, 1, 0);
  STAGE_B(1, 0, 1); STAGE_A(1, 0, 1); STAGE_B(1, 1, 1);
  asm volatile("s_waitcnt vmcnt(6)" ::: "memory");
  __builtin_amdgcn_s_barrier();

#define PH(MH_, NH_, RB_, VM_, BUF_, ...) \
  phase_t<MH_, NH_, RB_, VM_>(aB0 + (BUF_) * 32768, bB0 + (BUF_) * 32768, \
                              s0v, s1v, Ar, Br, acc, [&]() { __VA_ARGS__ })

  const int NI = K >> 7;  // iterations; 2 K-tiles each
  int i = 0;
  for (; i < NI - 1; ++i) {
    const int ktb = 2 * i + 1, ktc = 2 * i + 2, ktd = 2 * i + 3;
    PH(0, 0, true,  -1, 0, STAGE_A(1, 1, ktb); );
    PH(1, 0, false, -1, 0, STAGE_B(0, 0, ktc); );
    PH(0, 1, true,  -1, 0, );
    PH(1, 1, false,  6, 0, STAGE_A(0, 0, ktc); STAGE_B(0, 1, ktc); );
    PH(0, 0, true,  -1, 1, STAGE_A(0, 1, ktc); );
    PH(1, 0, false, -1, 1, STAGE_B(1, 0, ktd); );
    PH(0, 1, true,  -1, 1, );
    PH(1, 1, false,  6, 1, STAGE_A(1, 0, ktd); STAGE_B(1, 1, ktd); );
  }
  // peeled last iteration: finish staging tile b, drain, no further stages
  {
    const int ktb = 2 * i + 1;
    PH(0, 0, true,  -1, 0, STAGE_A(1, 1, ktb); );
    PH(1, 0, false, -1, 0, );
    PH(0, 1, true,  -1, 0, );
    PH(1, 1, false,  0, 0, );
    PH(0, 0, true,  -1, 1, );
    PH(1, 0, false, -1, 1, );
    PH(0, 1, true,  -1, 1, );
    PH(1, 1, false, -1, 1, );
  }
#undef PH
#undef STAGE_A
#undef STAGE_B

  // ---- epilogue: bias + relu + bf16 store
  // C/D layout: col = lane&15, row = (lane>>4)*4 + j   [measured m89]
#pragma unroll
  for (int mh = 0; mh < 2; ++mh)
#pragma unroll
    for (int nh = 0; nh < 2; ++nh)
#pragma unroll
      for (int m = 0; m < 4; ++m)
#pragma unroll
        for (int nf = 0; nf < 2; ++nf) {
          const int row = row0 + wr * 128 + mh * 64 + m * 16 + fq * 4;
          const int col = col0 + wc * 64 + nh * 32 + nf * 16 + fr;
          const float bv = bias[col];
          const size_t base = (size_t)row * N + col;
#pragma unroll
          for (int j = 0; j < 4; ++j) {
            float v = acc[mh][nh][m][nf][j] + bv;
            v = fmaxf(v, 0.0f);
            C[base + (size_t)j * N] = f2bf(v);
          }
        }
}

// ---------------------------------------------------------------------------
// logits (K=4096, N=10) + softmax -> probs[B,10]; one wave per row; h2 bf16
// ---------------------------------------------------------------------------
__global__ __launch_bounds__(256) void logits_softmax_kernel(
    const uint16_t* __restrict__ h2, const float* __restrict__ W3,
    const float* __restrict__ b3, float* __restrict__ probs, int B) {
  const int wave = threadIdx.x >> 6;
  const int lane = threadIdx.x & 63;
  const int row  = blockIdx.x * 4 + wave;
  if (row >= B) return;

  const uint16_t* hrow = h2 + (size_t)row * H_DIM;
  float acc[N_CLASSES];
#pragma unroll
  for (int c = 0; c < N_CLASSES; ++c) acc[c] = 0.0f;

#pragma unroll
  for (int it = 0; it < H_DIM / (64 * 8); ++it) {
    const int k0 = (it * 64 + lane) * 8;
    ushort4 u0 = *reinterpret_cast<const ushort4*>(hrow + k0);
    ushort4 u1 = *reinterpret_cast<const ushort4*>(hrow + k0 + 4);
    float hv[8] = {bf2f(u0.x), bf2f(u0.y), bf2f(u0.z), bf2f(u0.w),
                   bf2f(u1.x), bf2f(u1.y), bf2f(u1.z), bf2f(u1.w)};
#pragma unroll
    for (int q = 0; q < 8; ++q) {
      const float* wrow = W3 + (size_t)(k0 + q) * N_CLASSES;
#pragma unroll
      for (int c = 0; c < N_CLASSES; ++c) acc[c] = fmaf(hv[q], wrow[c], acc[c]);
    }
  }

#pragma unroll
  for (int c = 0; c < N_CLASSES; ++c) {
#pragma unroll
    for (int s = 32; s >= 1; s >>= 1) acc[c] += __shfl_xor(acc[c], s, 64);
  }

  if (lane == 0) {
    float l[N_CLASSES], m = -3.0e38f;
#pragma unroll
    for (int c = 0; c < N_CLASSES; ++c) {
      l[c] = acc[c] + b3[c];
      m = fmaxf(m, l[c]);
    }
    float sum = 0.0f;
#pragma unroll
    for (int c = 0; c < N_CLASSES; ++c) {
      l[c] = expf(l[c] - m);
      sum += l[c];
    }
    const float inv = 1.0f / sum;
#pragma unroll
    for (int c = 0; c < N_CLASSES; ++c) probs[row * N_CLASSES + c] = l[c] * inv;
  }
}

// ---------------------------------------------------------------------------
// launch.  ws layout (bf16 unless noted), total ~182 MB:
//   xb[8192*896] w1t[4096*896] w2t[4096*4096] h1[8192*4096] h2[8192*4096]
//   probs f32[8192*10]
// ---------------------------------------------------------------------------
extern "C" void kernel_launch(void* const* d_in, const int* in_sizes, int n_in,
                              void* d_out, int out_size, void* d_ws, size_t ws_size,
                              hipStream_t stream) {
  const float* x  = (const float*)d_in[0];
  const float* W1 = (const float*)d_in[1];
  const float* b1 = (const float*)d_in[2];
  const float* W2 = (const float*)d_in[3];
  const float* b2 = (const float*)d_in[4];
  const float* W3 = (const float*)d_in[5];
  const float* b3 = (const float*)d_in[6];
  float* out = (float*)d_out;

  uint16_t* xb  = (uint16_t*)d_ws;
  uint16_t* w1t = xb  + (size_t)B_SZ * KP1;
  uint16_t* w2t = w1t + (size_t)H_DIM * KP1;
  uint16_t* h1  = w2t + (size_t)H_DIM * H_DIM;
  uint16_t* h2  = h1  + (size_t)B_SZ * H_DIM;
  float* probs  = (float*)(h2 + (size_t)B_SZ * H_DIM);

  // allow 128 KiB dynamic LDS for the 8-phase GEMM (host-side attr, capture-safe)
  static bool attr_set = false;
  (void)hipFuncSetAttribute((const void*)gemm256_bf16,
                            hipFuncAttributeMaxDynamicSharedMemorySize, 131072);
  (void)attr_set;

  dim3 blk(256);

  // input conversions
  convert_pad_x<<<dim3((B_SZ * KP1 + 255) / 256), blk, 0, stream>>>(x, xb);
  transpose_convert<<<dim3(H_DIM / 32, KP1 / 32), blk, 0, stream>>>(W1, w1t, D_IN, H_DIM, KP1);
  transpose_convert<<<dim3(H_DIM / 32, H_DIM / 32), blk, 0, stream>>>(W2, w2t, H_DIM, H_DIM, H_DIM);

  // layer 1: h1 = relu(xb @ w1t^T + b1)   [8192,896]x[896,4096]
  gemm256_bf16<<<dim3(H_DIM / 256, B_SZ / 256), dim3(512), 131072, stream>>>(
      xb, w1t, b1, h1, B_SZ, H_DIM, KP1);

  // layer 2: h2 = relu(h1 @ w2t^T + b2)   [8192,4096]x[4096,4096]
  gemm256_bf16<<<dim3(H_DIM / 256, B_SZ / 256), dim3(512), 131072, stream>>>(
      h1, w2t, b2, h2, B_SZ, H_DIM, H_DIM);

  // layer 3 + softmax -> probs
  logits_softmax_kernel<<<dim3(B_SZ / 4), blk, 0, stream>>>(h2, W3, b3, probs, B_SZ);

  // circuit eval -> out[B]
  circuit_kernel<<<dim3(B_SZ / 256), blk, 0, stream>>>(probs, out, B_SZ);
}